// Round 1
// baseline (288.353 us; speedup 1.0000x reference)
//
#include <hip/hip_runtime.h>

#define CDIM 64
#define NDIM 4096
#define TILE 128
#define ROWP 72   // padded LDS row length in shorts (64 bf16 + 8 pad = 144 B)

typedef __attribute__((ext_vector_type(8))) short    bf16x8;
typedef __attribute__((ext_vector_type(4))) float    f32x4;
typedef __attribute__((ext_vector_type(4))) unsigned short ush4;

__device__ __forceinline__ unsigned short f2bf(float x) {
    unsigned int u = __builtin_bit_cast(unsigned int, x);
    u += 0x7fffu + ((u >> 16) & 1u);          // round-to-nearest-even
    return (unsigned short)(u >> 16);
}

__device__ __forceinline__ float bf2f(unsigned short s) {
    unsigned int u = ((unsigned int)s) << 16;
    return __builtin_bit_cast(float, u);
}

__global__ __launch_bounds__(256)
void distmap_kernel(const float* __restrict__ A,
                    const float* __restrict__ B,
                    float* __restrict__ D) {
    // LDS: tiles transposed to [n][c] so MFMA fragments are contiguous in k.
    __shared__ unsigned short At[TILE * ROWP];   // 18 KiB
    __shared__ unsigned short Bt[TILE * ROWP];   // 18 KiB
    __shared__ float aa_s[TILE];
    __shared__ float bb_s[TILE];

    const int t  = threadIdx.x;
    const int j0 = blockIdx.x * TILE;
    const int i0 = blockIdx.y * TILE;
    const int bz = blockIdx.z;

    const float* Ab = A + (size_t)bz * CDIM * NDIM;
    const float* Bb = B + (size_t)bz * CDIM * NDIM;

    // ---- stage both tiles: global [c][n] fp32 -> LDS [n][c] bf16 ----
    {
        const int f  = t & 31;   // n-block (n = 4f .. 4f+3)
        const int cb = t >> 5;   // c-block base (0..7)
        for (int s = 0; s < 2; ++s) {
            const int c = 4 * (cb + 8 * s);          // 0..60 step 4
            f32x4 ra[4], rb[4];
            for (int r = 0; r < 4; ++r) {
                ra[r] = *(const f32x4*)(Ab + (size_t)(c + r) * NDIM + i0 + 4 * f);
                rb[r] = *(const f32x4*)(Bb + (size_t)(c + r) * NDIM + j0 + 4 * f);
            }
            for (int q = 0; q < 4; ++q) {
                ush4 wa, wb;
                wa.x = f2bf(ra[0][q]); wa.y = f2bf(ra[1][q]);
                wa.z = f2bf(ra[2][q]); wa.w = f2bf(ra[3][q]);
                wb.x = f2bf(rb[0][q]); wb.y = f2bf(rb[1][q]);
                wb.z = f2bf(rb[2][q]); wb.w = f2bf(rb[3][q]);
                *(ush4*)&At[(4 * f + q) * ROWP + c] = wa;
                *(ush4*)&Bt[(4 * f + q) * ROWP + c] = wb;
            }
        }
    }
    __syncthreads();

    // ---- squared norms from the SAME bf16 values (consistent rounding) ----
    {
        const int r = t & 127;
        const unsigned short* src = (t < 128) ? &At[r * ROWP] : &Bt[r * ROWP];
        float s = 0.f;
        for (int k8 = 0; k8 < 8; ++k8) {
            bf16x8 v8 = *(const bf16x8*)(src + k8 * 8);
            for (int e = 0; e < 8; ++e) {
                float v = bf2f((unsigned short)v8[e]);
                s += v * v;
            }
        }
        if (t < 128) aa_s[r] = s; else bb_s[r] = s;
    }
    __syncthreads();

    // ---- MFMA: each wave computes 2 i-tiles x 8 j-tiles of 16x16 ----
    const int wv   = t >> 6;
    const int lane = t & 63;
    const int lm   = lane & 15;
    const int lq   = lane >> 4;        // 0..3
    const int kb   = lq * 8;           // k-offset in shorts

    bf16x8 afr[2][2];
    for (int ti = 0; ti < 2; ++ti) {
        const int row = (2 * wv + ti) * 16 + lm;
        afr[ti][0] = *(const bf16x8*)&At[row * ROWP + kb];
        afr[ti][1] = *(const bf16x8*)&At[row * ROWP + 32 + kb];
    }

    f32x4 acc[2][8];
    for (int ti = 0; ti < 2; ++ti)
        for (int tj = 0; tj < 8; ++tj)
            acc[ti][tj] = (f32x4){0.f, 0.f, 0.f, 0.f};

    for (int tj = 0; tj < 8; ++tj) {
        const int row = tj * 16 + lm;
        bf16x8 b0 = *(const bf16x8*)&Bt[row * ROWP + kb];
        bf16x8 b1 = *(const bf16x8*)&Bt[row * ROWP + 32 + kb];
        acc[0][tj] = __builtin_amdgcn_mfma_f32_16x16x32_bf16(afr[0][0], b0, acc[0][tj], 0, 0, 0);
        acc[0][tj] = __builtin_amdgcn_mfma_f32_16x16x32_bf16(afr[0][1], b1, acc[0][tj], 0, 0, 0);
        acc[1][tj] = __builtin_amdgcn_mfma_f32_16x16x32_bf16(afr[1][0], b0, acc[1][tj], 0, 0, 0);
        acc[1][tj] = __builtin_amdgcn_mfma_f32_16x16x32_bf16(afr[1][1], b1, acc[1][tj], 0, 0, 0);
    }

    // ---- epilogue: d = aa + bb - 2*ab; C-layout col=lane&15, row=lq*4+r ----
    float* Db = D + (size_t)bz * NDIM * NDIM;
    for (int ti = 0; ti < 2; ++ti) {
        const int ibase = (2 * wv + ti) * 16 + lq * 4;
        f32x4 aav = *(const f32x4*)&aa_s[ibase];
        for (int tj = 0; tj < 8; ++tj) {
            const int jl = tj * 16 + lm;
            const float bbv = bb_s[jl];
            float* drow = Db + (size_t)(i0 + ibase) * NDIM + (j0 + jl);
            for (int r = 0; r < 4; ++r) {
                drow[(size_t)r * NDIM] = aav[r] + bbv - 2.0f * acc[ti][tj][r];
            }
        }
    }
}

extern "C" void kernel_launch(void* const* d_in, const int* in_sizes, int n_in,
                              void* d_out, int out_size, void* d_ws, size_t ws_size,
                              hipStream_t stream) {
    const float* a = (const float*)d_in[0];
    const float* b = (const float*)d_in[1];
    float* out = (float*)d_out;
    const int batch = in_sizes[0] / (CDIM * NDIM);   // = 4
    dim3 grid(NDIM / TILE, NDIM / TILE, batch);
    distmap_kernel<<<grid, dim3(256), 0, stream>>>(a, b, out);
}